// Round 18
// baseline (130.453 us; speedup 1.0000x reference)
//
#include <hip/hip_runtime.h>
#include <hip/hip_bf16.h>
#include <stdint.h>

#define B_ 2
#define N_ 2048
#define H_ 16
#define DIM_ 1024
#define NH3 3072
#define ROWS (B_*N_)   // 4096
#define BHN (B_*H_*N_) // 65536

typedef __attribute__((ext_vector_type(8))) short bf16x8;
typedef __attribute__((ext_vector_type(4))) float f32x4;
typedef unsigned short u16;

__device__ __forceinline__ u16 f2bf(float f){
  union { float f; uint32_t u; } v; v.f = f;
  return (u16)((v.u + 0x7fffu + ((v.u >> 16) & 1u)) >> 16);
}

#if __has_builtin(__builtin_amdgcn_exp2f)
#define EXP2F(x) __builtin_amdgcn_exp2f(x)
#else
#define EXP2F(x) __expf((x) * 0.6931471805599453f)
#endif
#if __has_builtin(__builtin_amdgcn_rcpf)
#define RCPF(x) __builtin_amdgcn_rcpf(x)
#else
#define RCPF(x) (1.0f / (x))
#endif

#define GLL16(g, l) __builtin_amdgcn_global_load_lds( \
    (const __attribute__((address_space(1))) void*)(g), \
    (__attribute__((address_space(3))) void*)(l), 16, 0, 0)

// ---------------- fused prep: rmsnorm (0..4095) | transpose (4096..8191) | rope (8192..8703) ----------------
__global__ __launch_bounds__(256) void k_prep(
    const float* __restrict__ x, const float* __restrict__ gamma,
    const float* __restrict__ wqkv, const float* __restrict__ wout,
    const int* __restrict__ mods,
    u16* __restrict__ xn, u16* __restrict__ wqkvT, u16* __restrict__ woutT,
    float* __restrict__ cosT, float* __restrict__ sinT)
{
  __shared__ float tile[32][33];
  const int bx = blockIdx.x;
  const int tid = threadIdx.x;
  if (bx < 4096){
    const int row = bx;
    const float4 xv = ((const float4*)(x + (size_t)row*DIM_))[tid];
    float ss = xv.x*xv.x + xv.y*xv.y + xv.z*xv.z + xv.w*xv.w;
#pragma unroll
    for (int d = 1; d < 64; d <<= 1) ss += __shfl_xor(ss, d);
    if ((tid & 63) == 0) tile[1][tid >> 6] = ss;
    __syncthreads();
    float tot = tile[1][0] + tile[1][1] + tile[1][2] + tile[1][3];
    float scl = 32.0f / fmaxf(sqrtf(tot), 1e-12f);   // sqrt(1024)=32
    const float4 gv = ((const float4*)gamma)[tid];
    ushort4 o;
    o.x = f2bf(xv.x * scl * (gv.x + 1.0f));
    o.y = f2bf(xv.y * scl * (gv.y + 1.0f));
    o.z = f2bf(xv.z * scl * (gv.z + 1.0f));
    o.w = f2bf(xv.w * scl * (gv.w + 1.0f));
    ((ushort4*)(xn + (size_t)row*DIM_))[tid] = o;
  } else if (bx < 8192){
    const int t = bx - 4096;
    const int bxx = t & 127, by = t >> 7;
    const float* src; u16* dst; int C, bc;
    if (bxx < 96){ src = wqkv; dst = wqkvT; C = NH3;  bc = bxx*32; }
    else         { src = wout; dst = woutT; C = DIM_; bc = (bxx-96)*32; }
    const int R = DIM_;
    const int tx = tid & 31, ty = tid >> 5;
    const int br = by * 32;
#pragma unroll
    for (int i = 0; i < 32; i += 8)
      tile[ty + i][tx] = src[(size_t)(br + ty + i)*C + bc + tx];
    __syncthreads();
#pragma unroll
    for (int i = 0; i < 32; i += 8)
      dst[(size_t)(bc + ty + i)*R + br + tx] = f2bf(tile[tx][ty + i]);
  } else {
    const int t = (bx - 8192)*256 + tid;
    const int f = t & 31, bn = t >> 5;
    const int b = bn >> 11, n = bn & (N_-1);
    int cum = 0;
#pragma unroll
    for (int m = 0; m < 4; ++m){
      const int off = mods[(b*4 + m)*3 + 1];
      const int len = mods[(b*4 + m)*3 + 2];
      cum += min(max(n - off, 0), len - 1);
    }
    const float pos = (float)(n - cum);
    const float inv = powf(10000.0f, -(float)(2*f) / 64.0f);
    float s, c;
    sincosf(pos * inv, &s, &c);
    cosT[t] = c; sinT[t] = s;
  }
}

// ---------------- BMx128 bf16 MFMA GEMM: C = A @ Bt^T ----------------
template<int MODE, int BM>
__global__ __launch_bounds__(256) void k_gemm(
    const u16* __restrict__ A, const u16* __restrict__ Bt,
    int K, int Nc,
    float* __restrict__ outf,
    const float* __restrict__ cosT, const float* __restrict__ sinT,
    u16* __restrict__ qo, u16* __restrict__ ko, u16* __restrict__ vt)
{
  constexpr int MR = BM/32;
  constexpr int RA = BM/8;
  constexpr int CNT = (RA + 16)/4;
  __shared__ u16 lA[BM*64];
  __shared__ u16 lB[128*64];
  const int tid = threadIdx.x;
  const int wid = tid >> 6, lane = tid & 63;
  const int nx = gridDim.x;
  const int orig = blockIdx.y * nx + blockIdx.x;
  const int qq = (nx * gridDim.y) >> 3;
  const int wgid = (orig & 7) * qq + (orig >> 3);
  const int m0 = (wgid % nx) * BM, n0 = (wgid / nx) * 128;
  const int wm = wid >> 1, wn = wid & 1;
  const int srow = lane >> 3, sch = lane & 7;
  const int r16 = lane & 15, g4 = lane >> 4;
  f32x4 acc[MR][4] = {};
  const int ksteps = K >> 6;
  for (int kt = 0; kt < ksteps; ++kt){
    const int kb = kt*64;
    const int gch = sch ^ srow;
#pragma unroll
    for (int i = 0; i < CNT; ++i){
      const int reg = wid*CNT + i;
      if (reg < RA){
        const int row = reg*8 + srow;
        GLL16(A + (size_t)(m0 + row)*K + kb + gch*8, &lA[reg*512]);
      } else {
        const int r2 = reg - RA;
        const int row = r2*8 + srow;
        GLL16(Bt + (size_t)(n0 + row)*K + kb + gch*8, &lB[r2*512]);
      }
    }
    __syncthreads();
#pragma unroll
    for (int t = 0; t < 2; ++t){
      bf16x8 af[MR], bfr[4];
#pragma unroll
      for (int m = 0; m < MR; ++m){
        int row = wm*(BM/2) + m*16 + r16;
        int ch = (t*4 + g4) ^ (r16 & 7);
        af[m] = *(const bf16x8*)&lA[row*64 + ch*8];
      }
#pragma unroll
      for (int n = 0; n < 4; ++n){
        int row = wn*64 + n*16 + r16;
        int ch = (t*4 + g4) ^ (r16 & 7);
        bfr[n] = *(const bf16x8*)&lB[row*64 + ch*8];
      }
#pragma unroll
      for (int m = 0; m < MR; ++m)
#pragma unroll
        for (int n = 0; n < 4; ++n)
          acc[m][n] = __builtin_amdgcn_mfma_f32_16x16x32_bf16(af[m], bfr[n], acc[m][n], 0, 0, 0);
    }
    __syncthreads();
  }
#pragma unroll
  for (int m = 0; m < MR; ++m){
#pragma unroll
    for (int n = 0; n < 4; ++n){
      if constexpr (MODE == 0){
        const int gcol = n0 + wn*64 + n*16 + r16;
        const int s3 = gcol >> 10, hh = (gcol >> 6) & 15, d = gcol & 63;
        const int grow0 = m0 + wm*(BM/2) + m*16 + g4*4;
        const int b = grow0 >> 11, nn0 = grow0 & (N_-1);
        const size_t hb = (size_t)(b*H_ + hh);
        if (s3 == 2){
          uint32_t w01, w23;
          asm("v_cvt_pk_bf16_f32 %0, %1, %2" : "=v"(w01) : "v"(acc[m][n][0]), "v"(acc[m][n][1]));
          asm("v_cvt_pk_bf16_f32 %0, %1, %2" : "=v"(w23) : "v"(acc[m][n][2]), "v"(acc[m][n][3]));
          *reinterpret_cast<uint2*>(&vt[(hb*64 + d)*N_ + nn0]) = make_uint2(w01, w23);
        } else {
#pragma unroll
          for (int r = 0; r < 4; ++r){
            const float v = acc[m][n][r];
            const float part = __shfl_xor(v, 1);
            const int nn = nn0 + r;
            const int pidx = (b*N_ + nn)*32 + (d >> 1);
            const float c = cosT[pidx], sn = sinT[pidx];
            const float rot = (d & 1) ? (v*c + part*sn) : (v*c - part*sn);
            const u16 val = f2bf(rot);
            if (s3 == 0) qo[(hb*N_ + nn)*64 + d] = val;
            else         ko[(hb*N_ + nn)*64 + d] = val;
          }
        }
      } else {
#pragma unroll
        for (int r = 0; r < 4; ++r){
          const int grow = m0 + wm*(BM/2) + m*16 + g4*4 + r;
          const int gcol = n0 + wn*64 + n*16 + r16;
          outf[(size_t)grow*Nc + gcol] = acc[m][n][r];
        }
      }
    }
  }
}

// ---------------- fused attention: 4 waves x 32 q-rows (K/V frag reuse x2) ----------------
// Per 128-row block-tile the replicated K/V LDS reads halve vs 16-rows/wave:
// each fragment read feeds TWO q-half MFMAs. 256-thread blocks, grid 512.
#define PST 68   // P LDS row stride: 34 dwords -> uniform bank distribution for b64 ops
__global__ __launch_bounds__(256) void k_attn(
    const u16* __restrict__ qb, const u16* __restrict__ kb, const u16* __restrict__ vt,
    const int* __restrict__ mods, u16* __restrict__ xo)
{
  __shared__ u16 lK[64*64];
  __shared__ u16 lV[64*64];
  __shared__ u16 lP[4*32*PST];
  const int tid = threadIdx.x, wid = tid >> 6, lane = tid & 63;
  const int id = blockIdx.x;          // 0..511
  const int xcd = id & 7, rank = id >> 3;   // rank 0..63 per XCD
  const int bh = xcd + 8*(rank & 3);
  const int qslot = rank >> 2;        // 0..15
  const int tp = (qslot < 8) ? (15 - qslot) : (qslot - 8);  // complementary pairs
  const int b = bh >> 4, h = bh & 15;
  const int r16 = lane & 15, g4 = lane >> 4;
  const int srow = lane >> 3, sch = lane & 7;
  int moff[4], mend[4];
#pragma unroll
  for (int m = 0; m < 4; ++m){
    moff[m] = mods[(b*4+m)*3+1];
    mend[m] = moff[m] + mods[(b*4+m)*3+2];
  }
  const u16* kbase = kb + (size_t)bh*N_*64;
  const u16* vbase = vt + (size_t)bh*64*N_;
  u16* lPw = &lP[wid*32*PST];

  const int q0 = tp*128 + wid*32;     // this wave's 32 q-rows
  const int iA = q0 + r16;            // lane's q-row, half A
  const int iB = q0 + 16 + r16;       // lane's q-row, half B
  const int imax = tp*128 + 127;      // block max q-row (block-uniform skip)
  int jmaxA = 0, jmaxB = 0, jmax0 = 0;
#pragma unroll
  for (int m = 0; m < 4; ++m){
    if (iA >= moff[m]) jmaxA = max(jmaxA, mend[m]);
    if (iB >= moff[m]) jmaxB = max(jmaxB, mend[m]);
    if (q0 >= moff[m]) jmax0 = max(jmax0, mend[m]);
  }
  const int thrmin = max(q0, jmax0 - 1);   // wave-uniform lower bound of thr
  const u16* qrowA = qb + ((size_t)bh*N_ + iA)*64;
  const u16* qrowB = qb + ((size_t)bh*N_ + iB)*64;
  const bf16x8 aqA0 = *(const bf16x8*)&qrowA[g4*8];
  const bf16x8 aqA1 = *(const bf16x8*)&qrowA[32 + g4*8];
  const bf16x8 aqB0 = *(const bf16x8*)&qrowB[g4*8];
  const bf16x8 aqB1 = *(const bf16x8*)&qrowB[32 + g4*8];
  f32x4 oA[4] = {}, oB[4] = {};
  f32x4 acc_sA = {}, acc_sB = {};
  bf16x8 ones;
#pragma unroll
  for (int j = 0; j < 8; ++j) ones[j] = (short)0x3F80;  // bf16 1.0

  // g2(s) = 50*tanh(s*0.125/50)*log2e as odd series in s (w = s^2), 2 terms
  const float D1 = 0.18033688011112043f;
  const float D3 = -3.7570183356483704e-07f;

  for (int kt = 0; kt < N_/64; ++kt){
    bool proc = (kt*64 <= imax);
    if (!proc){
#pragma unroll
      for (int m = 0; m < 4; ++m)
        if (imax >= moff[m] && kt*64 < mend[m]) proc = true;
    }
    if (!proc) continue;             // block-uniform skip
    __syncthreads();                 // previous-iter readers done
    {
      // 4 waves x {2 K regions + 2 V regions} (8 rows each)
      const int gch = sch ^ srow;
#pragma unroll
      for (int ld = 0; ld < 2; ++ld){
        const int reg = wid*2 + ld;
        GLL16(kbase + (size_t)(kt*64 + reg*8 + srow)*64 + gch*8, &lK[reg*512]);
        GLL16(vbase + (size_t)(reg*8 + srow)*N_ + kt*64 + gch*8, &lV[reg*512]);
      }
    }
    __syncthreads();
    // S^T = K @ Q^T for both q-halves; K-frag read once, used twice
    f32x4 s0[4] = {}, s1[4] = {};
    __builtin_amdgcn_s_setprio(1);
#pragma unroll
    for (int cb = 0; cb < 4; ++cb){
#pragma unroll
      for (int t = 0; t < 2; ++t){
        int row = cb*16 + r16;
        int ch = (t*4 + g4) ^ (row & 7);
        bf16x8 bk = *(const bf16x8*)&lK[row*64 + ch*8];
        s0[cb] = __builtin_amdgcn_mfma_f32_16x16x32_bf16(bk, t ? aqA1 : aqA0, s0[cb], 0, 0, 0);
        s1[cb] = __builtin_amdgcn_mfma_f32_16x16x32_bf16(bk, t ? aqB1 : aqB0, s1[cb], 0, 0, 0);
      }
    }
    __builtin_amdgcn_s_setprio(0);
    const int thrA = max(iA, jmaxA - 1) - kt*64;     // keep <=> k_local <= thr
    const int thrB = max(iB, jmaxB - 1) - kt*64;
    const bool nomask = (kt*64 + 63 <= thrmin);      // wave-uniform fully-kept tile
#pragma unroll
    for (int half = 0; half < 2; ++half){
      const f32x4* sH = half ? s1 : s0;
      const int thr = half ? thrB : thrA;
#pragma unroll
      for (int cb = 0; cb < 4; ++cb){
        float p[4];
#pragma unroll
        for (int r = 0; r < 4; ++r){
          const float sv = sH[cb][r];
          const float w = sv*sv;
          p[r] = EXP2F(sv * fmaf(w, D3, D1));
        }
        if (!nomask){
#pragma unroll
          for (int r = 0; r < 4; ++r)
            p[r] = (cb*16 + g4*4 + r <= thr) ? p[r] : 0.0f;
        }
        uint32_t w01, w23;
        asm("v_cvt_pk_bf16_f32 %0, %1, %2" : "=v"(w01) : "v"(p[0]), "v"(p[1]));
        asm("v_cvt_pk_bf16_f32 %0, %1, %2" : "=v"(w23) : "v"(p[2]), "v"(p[3]));
        *reinterpret_cast<uint2*>(&lPw[(half*16 + r16)*PST + cb*16 + g4*4]) = make_uint2(w01, w23);
      }
    }
    asm volatile("s_waitcnt lgkmcnt(0)" ::: "memory");
    __builtin_amdgcn_sched_barrier(0);
    union { uint2 hh[2]; bf16x8 v; } a0, a1, b0, b1;
    a0.hh[0] = *(const uint2*)&lPw[r16*PST + g4*8];
    a0.hh[1] = *(const uint2*)&lPw[r16*PST + g4*8 + 4];
    a1.hh[0] = *(const uint2*)&lPw[r16*PST + 32 + g4*8];
    a1.hh[1] = *(const uint2*)&lPw[r16*PST + 32 + g4*8 + 4];
    b0.hh[0] = *(const uint2*)&lPw[(16 + r16)*PST + g4*8];
    b0.hh[1] = *(const uint2*)&lPw[(16 + r16)*PST + g4*8 + 4];
    b1.hh[0] = *(const uint2*)&lPw[(16 + r16)*PST + 32 + g4*8];
    b1.hh[1] = *(const uint2*)&lPw[(16 + r16)*PST + 32 + g4*8 + 4];
    __builtin_amdgcn_s_setprio(1);
    acc_sA = __builtin_amdgcn_mfma_f32_16x16x32_bf16(a0.v, ones, acc_sA, 0, 0, 0);
    acc_sA = __builtin_amdgcn_mfma_f32_16x16x32_bf16(a1.v, ones, acc_sA, 0, 0, 0);
    acc_sB = __builtin_amdgcn_mfma_f32_16x16x32_bf16(b0.v, ones, acc_sB, 0, 0, 0);
    acc_sB = __builtin_amdgcn_mfma_f32_16x16x32_bf16(b1.v, ones, acc_sB, 0, 0, 0);
#pragma unroll
    for (int cb = 0; cb < 4; ++cb){
#pragma unroll
      for (int t = 0; t < 2; ++t){
        int d = cb*16 + r16;
        int ch = (t*4 + g4) ^ (d & 7);
        bf16x8 bv = *(const bf16x8*)&lV[d*64 + ch*8];   // read once, used twice
        oA[cb] = __builtin_amdgcn_mfma_f32_16x16x32_bf16(t ? a1.v : a0.v, bv, oA[cb], 0, 0, 0);
        oB[cb] = __builtin_amdgcn_mfma_f32_16x16x32_bf16(t ? b1.v : b0.v, bv, oB[cb], 0, 0, 0);
      }
    }
    __builtin_amdgcn_s_setprio(0);
  }
  // epilogue: normalize + store both halves
#pragma unroll
  for (int r = 0; r < 4; ++r){
    const float linvA = RCPF(acc_sA[r]);
    const float linvB = RCPF(acc_sB[r]);
    const int iqA = q0 + g4*4 + r;
    const int iqB = q0 + 16 + g4*4 + r;
#pragma unroll
    for (int cb = 0; cb < 4; ++cb){
      xo[(size_t)(b*N_ + iqA)*DIM_ + h*64 + cb*16 + r16] = f2bf(oA[cb][r]*linvA);
      xo[(size_t)(b*N_ + iqB)*DIM_ + h*64 + cb*16 + r16] = f2bf(oB[cb][r]*linvB);
    }
  }
}

extern "C" void kernel_launch(void* const* d_in, const int* in_sizes, int n_in,
                              void* d_out, int out_size, void* d_ws, size_t ws_size,
                              hipStream_t stream){
  const float* x     = (const float*)d_in[0];
  const int*   mods  = (const int*)d_in[1];
  const float* gamma = (const float*)d_in[2];
  const float* wqkv  = (const float*)d_in[3];
  const float* wout  = (const float*)d_in[4];
  float* outp = (float*)d_out;

  char* p = (char*)d_ws;
  auto alloc = [&](size_t bytes) -> char* {
    char* r = p; p += (bytes + 255) & ~(size_t)255; return r;
  };
  float* cosT  = (float*)alloc((size_t)B_*N_*32*4);
  float* sinT  = (float*)alloc((size_t)B_*N_*32*4);
  u16* wqkvT   = (u16*)alloc((size_t)NH3*DIM_*2);
  u16* woutT   = (u16*)alloc((size_t)DIM_*DIM_*2);
  u16* xn      = (u16*)alloc((size_t)ROWS*DIM_*2);
  u16* qbb     = (u16*)alloc((size_t)BHN*64*2);
  u16* kbb     = (u16*)alloc((size_t)BHN*64*2);
  u16* vtb     = (u16*)alloc((size_t)BHN*64*2);
  u16* xo      = (u16*)alloc((size_t)ROWS*DIM_*2);

  k_prep<<<8704, 256, 0, stream>>>(x, gamma, wqkv, wout, mods, xn, wqkvT, woutT, cosT, sinT);
  k_gemm<0,128><<<dim3(ROWS/128, NH3/128), 256, 0, stream>>>(xn, wqkvT, DIM_, NH3, nullptr, cosT, sinT, qbb, kbb, vtb);
  k_attn<<<512, 256, 0, stream>>>(qbb, kbb, vtb, mods, xo);
  k_gemm<1,64><<<dim3(ROWS/64, DIM_/128), 256, 0, stream>>>(xo, woutT, DIM_, DIM_, outp, nullptr, nullptr, nullptr, nullptr, nullptr);
}

// Round 19
// 128.920 us; speedup vs baseline: 1.0119x; 1.0119x over previous
//
#include <hip/hip_runtime.h>
#include <hip/hip_bf16.h>
#include <stdint.h>

#define B_ 2
#define N_ 2048
#define H_ 16
#define DIM_ 1024
#define NH3 3072
#define ROWS (B_*N_)   // 4096
#define BHN (B_*H_*N_) // 65536

typedef __attribute__((ext_vector_type(8))) short bf16x8;
typedef __attribute__((ext_vector_type(4))) float f32x4;
typedef __attribute__((ext_vector_type(16))) float f32x16;
typedef unsigned short u16;

__device__ __forceinline__ u16 f2bf(float f){
  union { float f; uint32_t u; } v; v.f = f;
  return (u16)((v.u + 0x7fffu + ((v.u >> 16) & 1u)) >> 16);
}

#if __has_builtin(__builtin_amdgcn_exp2f)
#define EXP2F(x) __builtin_amdgcn_exp2f(x)
#else
#define EXP2F(x) __expf((x) * 0.6931471805599453f)
#endif
#if __has_builtin(__builtin_amdgcn_rcpf)
#define RCPF(x) __builtin_amdgcn_rcpf(x)
#else
#define RCPF(x) (1.0f / (x))
#endif

#define GLL16(g, l) __builtin_amdgcn_global_load_lds( \
    (const __attribute__((address_space(1))) void*)(g), \
    (__attribute__((address_space(3))) void*)(l), 16, 0, 0)

// ---------------- fused prep: rmsnorm (0..4095) | transpose (4096..8191) | rope (8192..8703) ----------------
__global__ __launch_bounds__(256) void k_prep(
    const float* __restrict__ x, const float* __restrict__ gamma,
    const float* __restrict__ wqkv, const float* __restrict__ wout,
    const int* __restrict__ mods,
    u16* __restrict__ xn, u16* __restrict__ wqkvT, u16* __restrict__ woutT,
    float* __restrict__ cosT, float* __restrict__ sinT)
{
  __shared__ float tile[32][33];
  const int bx = blockIdx.x;
  const int tid = threadIdx.x;
  if (bx < 4096){
    const int row = bx;
    const float4 xv = ((const float4*)(x + (size_t)row*DIM_))[tid];
    float ss = xv.x*xv.x + xv.y*xv.y + xv.z*xv.z + xv.w*xv.w;
#pragma unroll
    for (int d = 1; d < 64; d <<= 1) ss += __shfl_xor(ss, d);
    if ((tid & 63) == 0) tile[1][tid >> 6] = ss;
    __syncthreads();
    float tot = tile[1][0] + tile[1][1] + tile[1][2] + tile[1][3];
    float scl = 32.0f / fmaxf(sqrtf(tot), 1e-12f);   // sqrt(1024)=32
    const float4 gv = ((const float4*)gamma)[tid];
    ushort4 o;
    o.x = f2bf(xv.x * scl * (gv.x + 1.0f));
    o.y = f2bf(xv.y * scl * (gv.y + 1.0f));
    o.z = f2bf(xv.z * scl * (gv.z + 1.0f));
    o.w = f2bf(xv.w * scl * (gv.w + 1.0f));
    ((ushort4*)(xn + (size_t)row*DIM_))[tid] = o;
  } else if (bx < 8192){
    const int t = bx - 4096;
    const int bxx = t & 127, by = t >> 7;
    const float* src; u16* dst; int C, bc;
    if (bxx < 96){ src = wqkv; dst = wqkvT; C = NH3;  bc = bxx*32; }
    else         { src = wout; dst = woutT; C = DIM_; bc = (bxx-96)*32; }
    const int R = DIM_;
    const int tx = tid & 31, ty = tid >> 5;
    const int br = by * 32;
#pragma unroll
    for (int i = 0; i < 32; i += 8)
      tile[ty + i][tx] = src[(size_t)(br + ty + i)*C + bc + tx];
    __syncthreads();
#pragma unroll
    for (int i = 0; i < 32; i += 8)
      dst[(size_t)(bc + ty + i)*R + br + tx] = f2bf(tile[tx][ty + i]);
  } else {
    const int t = (bx - 8192)*256 + tid;
    const int f = t & 31, bn = t >> 5;
    const int b = bn >> 11, n = bn & (N_-1);
    int cum = 0;
#pragma unroll
    for (int m = 0; m < 4; ++m){
      const int off = mods[(b*4 + m)*3 + 1];
      const int len = mods[(b*4 + m)*3 + 2];
      cum += min(max(n - off, 0), len - 1);
    }
    const float pos = (float)(n - cum);
    const float inv = powf(10000.0f, -(float)(2*f) / 64.0f);
    float s, c;
    sincosf(pos * inv, &s, &c);
    cosT[t] = c; sinT[t] = s;
  }
}

// ---------------- BMx128 bf16 MFMA GEMM: C = A @ Bt^T ----------------
template<int MODE, int BM>
__global__ __launch_bounds__(256) void k_gemm(
    const u16* __restrict__ A, const u16* __restrict__ Bt,
    int K, int Nc,
    float* __restrict__ outf,
    const float* __restrict__ cosT, const float* __restrict__ sinT,
    u16* __restrict__ qo, u16* __restrict__ ko, u16* __restrict__ vt)
{
  constexpr int MR = BM/32;
  constexpr int RA = BM/8;
  constexpr int CNT = (RA + 16)/4;
  __shared__ u16 lA[BM*64];
  __shared__ u16 lB[128*64];
  const int tid = threadIdx.x;
  const int wid = tid >> 6, lane = tid & 63;
  const int nx = gridDim.x;
  const int orig = blockIdx.y * nx + blockIdx.x;
  const int qq = (nx * gridDim.y) >> 3;
  const int wgid = (orig & 7) * qq + (orig >> 3);
  const int m0 = (wgid % nx) * BM, n0 = (wgid / nx) * 128;
  const int wm = wid >> 1, wn = wid & 1;
  const int srow = lane >> 3, sch = lane & 7;
  const int r16 = lane & 15, g4 = lane >> 4;
  f32x4 acc[MR][4] = {};
  const int ksteps = K >> 6;
  for (int kt = 0; kt < ksteps; ++kt){
    const int kb = kt*64;
    const int gch = sch ^ srow;
#pragma unroll
    for (int i = 0; i < CNT; ++i){
      const int reg = wid*CNT + i;
      if (reg < RA){
        const int row = reg*8 + srow;
        GLL16(A + (size_t)(m0 + row)*K + kb + gch*8, &lA[reg*512]);
      } else {
        const int r2 = reg - RA;
        const int row = r2*8 + srow;
        GLL16(Bt + (size_t)(n0 + row)*K + kb + gch*8, &lB[r2*512]);
      }
    }
    __syncthreads();
#pragma unroll
    for (int t = 0; t < 2; ++t){
      bf16x8 af[MR], bfr[4];
#pragma unroll
      for (int m = 0; m < MR; ++m){
        int row = wm*(BM/2) + m*16 + r16;
        int ch = (t*4 + g4) ^ (r16 & 7);
        af[m] = *(const bf16x8*)&lA[row*64 + ch*8];
      }
#pragma unroll
      for (int n = 0; n < 4; ++n){
        int row = wn*64 + n*16 + r16;
        int ch = (t*4 + g4) ^ (r16 & 7);
        bfr[n] = *(const bf16x8*)&lB[row*64 + ch*8];
      }
#pragma unroll
      for (int m = 0; m < MR; ++m)
#pragma unroll
        for (int n = 0; n < 4; ++n)
          acc[m][n] = __builtin_amdgcn_mfma_f32_16x16x32_bf16(af[m], bfr[n], acc[m][n], 0, 0, 0);
    }
    __syncthreads();
  }
#pragma unroll
  for (int m = 0; m < MR; ++m){
#pragma unroll
    for (int n = 0; n < 4; ++n){
      if constexpr (MODE == 0){
        const int gcol = n0 + wn*64 + n*16 + r16;
        const int s3 = gcol >> 10, hh = (gcol >> 6) & 15, d = gcol & 63;
        const int grow0 = m0 + wm*(BM/2) + m*16 + g4*4;
        const int b = grow0 >> 11, nn0 = grow0 & (N_-1);
        const size_t hb = (size_t)(b*H_ + hh);
        if (s3 == 2){
          uint32_t w01, w23;
          asm("v_cvt_pk_bf16_f32 %0, %1, %2" : "=v"(w01) : "v"(acc[m][n][0]), "v"(acc[m][n][1]));
          asm("v_cvt_pk_bf16_f32 %0, %1, %2" : "=v"(w23) : "v"(acc[m][n][2]), "v"(acc[m][n][3]));
          *reinterpret_cast<uint2*>(&vt[(hb*64 + d)*N_ + nn0]) = make_uint2(w01, w23);
        } else {
#pragma unroll
          for (int r = 0; r < 4; ++r){
            const float v = acc[m][n][r];
            const float part = __shfl_xor(v, 1);
            const int nn = nn0 + r;
            const int pidx = (b*N_ + nn)*32 + (d >> 1);
            const float c = cosT[pidx], sn = sinT[pidx];
            const float rot = (d & 1) ? (v*c + part*sn) : (v*c - part*sn);
            const u16 val = f2bf(rot);
            if (s3 == 0) qo[(hb*N_ + nn)*64 + d] = val;
            else         ko[(hb*N_ + nn)*64 + d] = val;
          }
        }
      } else {
#pragma unroll
        for (int r = 0; r < 4; ++r){
          const int grow = m0 + wm*(BM/2) + m*16 + g4*4 + r;
          const int gcol = n0 + wn*64 + n*16 + r16;
          outf[(size_t)grow*Nc + gcol] = acc[m][n][r];
        }
      }
    }
  }
}

// ---------------- fused attention: 32x32 MFMA, in-register P (permlane32_swap) ----------------
// 4 waves x 32 q-rows, grid 512 (complementary pairing). Swapped QK^T:
// S^T[k][q=lane&31], k = kb*32 + (reg&3)+8*(reg>>2)+4*hi. P never touches LDS:
// PV A-frag built from cvt_pk quads + v_permlane32_swap_b32 (T12 layout).
__global__ __launch_bounds__(256) void k_attn(
    const u16* __restrict__ qb, const u16* __restrict__ kb, const u16* __restrict__ vt,
    const int* __restrict__ mods, u16* __restrict__ xo)
{
  __shared__ u16 lK[64*64];
  __shared__ u16 lV[64*64];
  const int tid = threadIdx.x, wid = tid >> 6, lane = tid & 63;
  const int id = blockIdx.x;          // 0..511
  const int xcd = id & 7, rank = id >> 3;   // rank 0..63 per XCD
  const int bh = xcd + 8*(rank & 3);
  const int qslot = rank >> 2;        // 0..15
  const int tp = (qslot < 8) ? (15 - qslot) : (qslot - 8);  // complementary pairs
  const int b = bh >> 4, h = bh & 15;
  const int l31 = lane & 31, hi = lane >> 5;
  const int srow = lane >> 3, sch = lane & 7;
  int moff[4], mend[4];
#pragma unroll
  for (int m = 0; m < 4; ++m){
    moff[m] = mods[(b*4+m)*3+1];
    mend[m] = moff[m] + mods[(b*4+m)*3+2];
  }
  const u16* kbase = kb + (size_t)bh*N_*64;
  const u16* vbase = vt + (size_t)bh*64*N_;

  const int q0w = tp*128 + wid*32;    // this wave's 32 q-rows
  const int qG  = q0w + l31;          // this lane's q-row
  const int imax = tp*128 + 127;      // block max q-row (block-uniform skip)
  int jmax = 0, jmax0 = 0;
#pragma unroll
  for (int m = 0; m < 4; ++m){
    if (qG  >= moff[m]) jmax  = max(jmax,  mend[m]);
    if (q0w >= moff[m]) jmax0 = max(jmax0, mend[m]);
  }
  const int thrg = max(qG, jmax - 1);       // keep <=> k_global <= thrg (per lane)
  const int thrmin = max(q0w, jmax0 - 1);   // wave-uniform lower bound
  // Q fragments: B[j=q=l31][d = t*16 + hi*8 + jj]
  const u16* qrow = qb + ((size_t)bh*N_ + qG)*64;
  bf16x8 qf[4];
#pragma unroll
  for (int t = 0; t < 4; ++t)
    qf[t] = *(const bf16x8*)&qrow[t*16 + hi*8];

  f32x16 o0 = {}, o1 = {};            // PV accumulators (d-blocks 0,1)
  float lsum = 0.f;

  // g2(s) = 50*tanh(s*0.125/50)*log2e as odd series in s (w = s^2), 2 terms
  const float D1 = 0.18033688011112043f;
  const float D3 = -3.7570183356483704e-07f;

  for (int kt = 0; kt < N_/64; ++kt){
    bool proc = (kt*64 <= imax);
    if (!proc){
#pragma unroll
      for (int m = 0; m < 4; ++m)
        if (imax >= moff[m] && kt*64 < mend[m]) proc = true;
    }
    if (!proc) continue;             // block-uniform skip
    __syncthreads();                 // previous-iter readers done
    {
      // 4 waves x {2 K regions + 2 V regions} (8 rows each)
      const int gch = sch ^ srow;
#pragma unroll
      for (int ld = 0; ld < 2; ++ld){
        const int reg = wid*2 + ld;
        GLL16(kbase + (size_t)(kt*64 + reg*8 + srow)*64 + gch*8, &lK[reg*512]);
        GLL16(vbase + (size_t)(reg*8 + srow)*N_ + kt*64 + gch*8, &lV[reg*512]);
      }
    }
    __syncthreads();
    // QK^T: S^T = mfma32(K, Q). A=K[i=kb*32+l31][d], B=Q[j=qG][d]
    f32x16 s0 = {}, s1 = {};
    __builtin_amdgcn_s_setprio(1);
#pragma unroll
    for (int t = 0; t < 4; ++t){
      const int c = t*2 + hi;
      const int r0 = l31, r1 = 32 + l31;
      const bf16x8 k0 = *(const bf16x8*)&lK[r0*64 + (c ^ (r0 & 7))*8];
      const bf16x8 k1 = *(const bf16x8*)&lK[r1*64 + (c ^ (r1 & 7))*8];
      s0 = __builtin_amdgcn_mfma_f32_32x32x16_bf16(k0, qf[t], s0, 0, 0, 0);
      s1 = __builtin_amdgcn_mfma_f32_32x32x16_bf16(k1, qf[t], s1, 0, 0, 0);
    }
    __builtin_amdgcn_s_setprio(0);
    const int thr = thrg - kt*64;                    // keep <=> k_loc <= thr
    const bool nomask = (kt*64 + 63 <= thrmin);      // wave-uniform fully-kept tile
    // softcap -> p (masked), accumulate row-sum per lane
    float p0[16], p1[16];
#pragma unroll
    for (int reg = 0; reg < 16; ++reg){
      const int kb32 = (reg & 3) + 8*(reg >> 2);     // + 4*hi added below
      {
        const float sv = s0[reg];
        const float w = sv*sv;
        float p = EXP2F(sv * fmaf(w, D3, D1));
        if (!nomask) p = (kb32 + 4*hi <= thr) ? p : 0.0f;
        p0[reg] = p; lsum += p;
      }
      {
        const float sv = s1[reg];
        const float w = sv*sv;
        float p = EXP2F(sv * fmaf(w, D3, D1));
        if (!nomask) p = (32 + kb32 + 4*hi <= thr) ? p : 0.0f;
        p1[reg] = p; lsum += p;
      }
    }
    // build PV A-frags in-register: frag(kb,q32) = [X0,X1,Y0,Y1],
    // X = cvt_pk of quad s=2*q32 (regs q32*8+0..3), Y = quad s=2*q32+1 (regs q32*8+4..7),
    // then permlane32_swap(X0,Y0), (X1,Y1).
    bf16x8 pf[4];
#pragma unroll
    for (int ks = 0; ks < 4; ++ks){
      const float* pp = (ks < 2) ? p0 : p1;
      const int q32 = ks & 1;
      uint32_t X0, X1, Y0, Y1;
      asm("v_cvt_pk_bf16_f32 %0, %1, %2" : "=v"(X0) : "v"(pp[q32*8+0]), "v"(pp[q32*8+1]));
      asm("v_cvt_pk_bf16_f32 %0, %1, %2" : "=v"(X1) : "v"(pp[q32*8+2]), "v"(pp[q32*8+3]));
      asm("v_cvt_pk_bf16_f32 %0, %1, %2" : "=v"(Y0) : "v"(pp[q32*8+4]), "v"(pp[q32*8+5]));
      asm("v_cvt_pk_bf16_f32 %0, %1, %2" : "=v"(Y1) : "v"(pp[q32*8+6]), "v"(pp[q32*8+7]));
      asm volatile("v_permlane32_swap_b32 %0, %1" : "+v"(X0), "+v"(Y0));
      asm volatile("v_permlane32_swap_b32 %0, %1" : "+v"(X1), "+v"(Y1));
      union { uint32_t d[4]; bf16x8 v; } u;
      u.d[0] = X0; u.d[1] = X1; u.d[2] = Y0; u.d[3] = Y1;
      pf[ks] = u.v;
    }
    // PV: o[db] += mfma32(P, V). B=V[j=d=db*32+l31][k = ks*16 + hi*8 + jj]
    __builtin_amdgcn_s_setprio(1);
#pragma unroll
    for (int ks = 0; ks < 4; ++ks){
      const int d0 = l31, d1 = 32 + l31;
      const int c = ks*2 + hi;
      const bf16x8 v0 = *(const bf16x8*)&lV[d0*64 + (c ^ (d0 & 7))*8];
      const bf16x8 v1 = *(const bf16x8*)&lV[d1*64 + (c ^ (d1 & 7))*8];
      o0 = __builtin_amdgcn_mfma_f32_32x32x16_bf16(pf[ks], v0, o0, 0, 0, 0);
      o1 = __builtin_amdgcn_mfma_f32_32x32x16_bf16(pf[ks], v1, o1, 0, 0, 0);
    }
    __builtin_amdgcn_s_setprio(0);
  }
  // row-sum: lane has partial for q=qG over its k-half; partner half in lane^32
  lsum += __shfl_xor(lsum, 32);
  // epilogue: o[db] lane holds D[q_loc=(reg&3)+8*(reg>>2)+4*hi][d=db*32+l31]
#pragma unroll
  for (int reg = 0; reg < 16; ++reg){
    const int q_loc = (reg & 3) + 8*(reg >> 2) + 4*hi;
    const float linv = RCPF(__shfl(lsum, q_loc));   // lane q_loc holds sum for q0w+q_loc
    const int iq = q0w + q_loc;
    xo[(size_t)(b*N_ + iq)*DIM_ + h*64 + l31]      = f2bf(o0[reg]*linv);
    xo[(size_t)(b*N_ + iq)*DIM_ + h*64 + 32 + l31] = f2bf(o1[reg]*linv);
  }
}

extern "C" void kernel_launch(void* const* d_in, const int* in_sizes, int n_in,
                              void* d_out, int out_size, void* d_ws, size_t ws_size,
                              hipStream_t stream){
  const float* x     = (const float*)d_in[0];
  const int*   mods  = (const int*)d_in[1];
  const float* gamma = (const float*)d_in[2];
  const float* wqkv  = (const float*)d_in[3];
  const float* wout  = (const float*)d_in[4];
  float* outp = (float*)d_out;

  char* p = (char*)d_ws;
  auto alloc = [&](size_t bytes) -> char* {
    char* r = p; p += (bytes + 255) & ~(size_t)255; return r;
  };
  float* cosT  = (float*)alloc((size_t)B_*N_*32*4);
  float* sinT  = (float*)alloc((size_t)B_*N_*32*4);
  u16* wqkvT   = (u16*)alloc((size_t)NH3*DIM_*2);
  u16* woutT   = (u16*)alloc((size_t)DIM_*DIM_*2);
  u16* xn      = (u16*)alloc((size_t)ROWS*DIM_*2);
  u16* qbb     = (u16*)alloc((size_t)BHN*64*2);
  u16* kbb     = (u16*)alloc((size_t)BHN*64*2);
  u16* vtb     = (u16*)alloc((size_t)BHN*64*2);
  u16* xo      = (u16*)alloc((size_t)ROWS*DIM_*2);

  k_prep<<<8704, 256, 0, stream>>>(x, gamma, wqkv, wout, mods, xn, wqkvT, woutT, cosT, sinT);
  k_gemm<0,128><<<dim3(ROWS/128, NH3/128), 256, 0, stream>>>(xn, wqkvT, DIM_, NH3, nullptr, cosT, sinT, qbb, kbb, vtb);
  k_attn<<<512, 256, 0, stream>>>(qbb, kbb, vtb, mods, xo);
  k_gemm<1,64><<<dim3(ROWS/64, DIM_/128), 256, 0, stream>>>(xo, woutT, DIM_, DIM_, outp, nullptr, nullptr, nullptr, nullptr, nullptr);
}

// Round 20
// 113.068 us; speedup vs baseline: 1.1538x; 1.1402x over previous
//
#include <hip/hip_runtime.h>
#include <hip/hip_bf16.h>
#include <stdint.h>

#define B_ 2
#define N_ 2048
#define H_ 16
#define DIM_ 1024
#define NH3 3072
#define ROWS (B_*N_)   // 4096
#define BHN (B_*H_*N_) // 65536

typedef __attribute__((ext_vector_type(8))) short bf16x8;
typedef __attribute__((ext_vector_type(4))) float f32x4;
typedef unsigned short u16;

__device__ __forceinline__ u16 f2bf(float f){
  union { float f; uint32_t u; } v; v.f = f;
  return (u16)((v.u + 0x7fffu + ((v.u >> 16) & 1u)) >> 16);
}

#if __has_builtin(__builtin_amdgcn_exp2f)
#define EXP2F(x) __builtin_amdgcn_exp2f(x)
#else
#define EXP2F(x) __expf((x) * 0.6931471805599453f)
#endif
#if __has_builtin(__builtin_amdgcn_rcpf)
#define RCPF(x) __builtin_amdgcn_rcpf(x)
#else
#define RCPF(x) (1.0f / (x))
#endif

#define GLL16(g, l) __builtin_amdgcn_global_load_lds( \
    (const __attribute__((address_space(1))) void*)(g), \
    (__attribute__((address_space(3))) void*)(l), 16, 0, 0)

// ---------------- fused prep: rmsnorm (0..4095) | transpose (4096..8191) | rope (8192..8703) ----------------
__global__ __launch_bounds__(256) void k_prep(
    const float* __restrict__ x, const float* __restrict__ gamma,
    const float* __restrict__ wqkv, const float* __restrict__ wout,
    const int* __restrict__ mods,
    u16* __restrict__ xn, u16* __restrict__ wqkvT, u16* __restrict__ woutT,
    float* __restrict__ cosT, float* __restrict__ sinT)
{
  __shared__ float tile[32][33];
  const int bx = blockIdx.x;
  const int tid = threadIdx.x;
  if (bx < 4096){
    const int row = bx;
    const float4 xv = ((const float4*)(x + (size_t)row*DIM_))[tid];
    float ss = xv.x*xv.x + xv.y*xv.y + xv.z*xv.z + xv.w*xv.w;
#pragma unroll
    for (int d = 1; d < 64; d <<= 1) ss += __shfl_xor(ss, d);
    if ((tid & 63) == 0) tile[1][tid >> 6] = ss;
    __syncthreads();
    float tot = tile[1][0] + tile[1][1] + tile[1][2] + tile[1][3];
    float scl = 32.0f / fmaxf(sqrtf(tot), 1e-12f);   // sqrt(1024)=32
    const float4 gv = ((const float4*)gamma)[tid];
    ushort4 o;
    o.x = f2bf(xv.x * scl * (gv.x + 1.0f));
    o.y = f2bf(xv.y * scl * (gv.y + 1.0f));
    o.z = f2bf(xv.z * scl * (gv.z + 1.0f));
    o.w = f2bf(xv.w * scl * (gv.w + 1.0f));
    ((ushort4*)(xn + (size_t)row*DIM_))[tid] = o;
  } else if (bx < 8192){
    const int t = bx - 4096;
    const int bxx = t & 127, by = t >> 7;
    const float* src; u16* dst; int C, bc;
    if (bxx < 96){ src = wqkv; dst = wqkvT; C = NH3;  bc = bxx*32; }
    else         { src = wout; dst = woutT; C = DIM_; bc = (bxx-96)*32; }
    const int R = DIM_;
    const int tx = tid & 31, ty = tid >> 5;
    const int br = by * 32;
#pragma unroll
    for (int i = 0; i < 32; i += 8)
      tile[ty + i][tx] = src[(size_t)(br + ty + i)*C + bc + tx];
    __syncthreads();
#pragma unroll
    for (int i = 0; i < 32; i += 8)
      dst[(size_t)(bc + ty + i)*R + br + tx] = f2bf(tile[tx][ty + i]);
  } else {
    const int t = (bx - 8192)*256 + tid;
    const int f = t & 31, bn = t >> 5;
    const int b = bn >> 11, n = bn & (N_-1);
    int cum = 0;
#pragma unroll
    for (int m = 0; m < 4; ++m){
      const int off = mods[(b*4 + m)*3 + 1];
      const int len = mods[(b*4 + m)*3 + 2];
      cum += min(max(n - off, 0), len - 1);
    }
    const float pos = (float)(n - cum);
    const float inv = powf(10000.0f, -(float)(2*f) / 64.0f);
    float s, c;
    sincosf(pos * inv, &s, &c);
    cosT[t] = c; sinT[t] = s;
  }
}

// ---------------- BMx128 bf16 MFMA GEMM: C = A @ Bt^T ----------------
template<int MODE, int BM>
__global__ __launch_bounds__(256) void k_gemm(
    const u16* __restrict__ A, const u16* __restrict__ Bt,
    int K, int Nc,
    float* __restrict__ outf,
    const float* __restrict__ cosT, const float* __restrict__ sinT,
    u16* __restrict__ qo, u16* __restrict__ ko, u16* __restrict__ vt)
{
  constexpr int MR = BM/32;
  constexpr int RA = BM/8;
  constexpr int CNT = (RA + 16)/4;
  __shared__ u16 lA[BM*64];
  __shared__ u16 lB[128*64];
  const int tid = threadIdx.x;
  const int wid = tid >> 6, lane = tid & 63;
  const int nx = gridDim.x;
  const int orig = blockIdx.y * nx + blockIdx.x;
  const int qq = (nx * gridDim.y) >> 3;
  const int wgid = (orig & 7) * qq + (orig >> 3);
  const int m0 = (wgid % nx) * BM, n0 = (wgid / nx) * 128;
  const int wm = wid >> 1, wn = wid & 1;
  const int srow = lane >> 3, sch = lane & 7;
  const int r16 = lane & 15, g4 = lane >> 4;
  f32x4 acc[MR][4] = {};
  const int ksteps = K >> 6;
  for (int kt = 0; kt < ksteps; ++kt){
    const int kb = kt*64;
    const int gch = sch ^ srow;
#pragma unroll
    for (int i = 0; i < CNT; ++i){
      const int reg = wid*CNT + i;
      if (reg < RA){
        const int row = reg*8 + srow;
        GLL16(A + (size_t)(m0 + row)*K + kb + gch*8, &lA[reg*512]);
      } else {
        const int r2 = reg - RA;
        const int row = r2*8 + srow;
        GLL16(Bt + (size_t)(n0 + row)*K + kb + gch*8, &lB[r2*512]);
      }
    }
    __syncthreads();
#pragma unroll
    for (int t = 0; t < 2; ++t){
      bf16x8 af[MR], bfr[4];
#pragma unroll
      for (int m = 0; m < MR; ++m){
        int row = wm*(BM/2) + m*16 + r16;
        int ch = (t*4 + g4) ^ (r16 & 7);
        af[m] = *(const bf16x8*)&lA[row*64 + ch*8];
      }
#pragma unroll
      for (int n = 0; n < 4; ++n){
        int row = wn*64 + n*16 + r16;
        int ch = (t*4 + g4) ^ (r16 & 7);
        bfr[n] = *(const bf16x8*)&lB[row*64 + ch*8];
      }
#pragma unroll
      for (int m = 0; m < MR; ++m)
#pragma unroll
        for (int n = 0; n < 4; ++n)
          acc[m][n] = __builtin_amdgcn_mfma_f32_16x16x32_bf16(af[m], bfr[n], acc[m][n], 0, 0, 0);
    }
    __syncthreads();
  }
#pragma unroll
  for (int m = 0; m < MR; ++m){
#pragma unroll
    for (int n = 0; n < 4; ++n){
      if constexpr (MODE == 0){
        const int gcol = n0 + wn*64 + n*16 + r16;
        const int s3 = gcol >> 10, hh = (gcol >> 6) & 15, d = gcol & 63;
        const int grow0 = m0 + wm*(BM/2) + m*16 + g4*4;
        const int b = grow0 >> 11, nn0 = grow0 & (N_-1);
        const size_t hb = (size_t)(b*H_ + hh);
        if (s3 == 2){
          uint32_t w01, w23;
          asm("v_cvt_pk_bf16_f32 %0, %1, %2" : "=v"(w01) : "v"(acc[m][n][0]), "v"(acc[m][n][1]));
          asm("v_cvt_pk_bf16_f32 %0, %1, %2" : "=v"(w23) : "v"(acc[m][n][2]), "v"(acc[m][n][3]));
          *reinterpret_cast<uint2*>(&vt[(hb*64 + d)*N_ + nn0]) = make_uint2(w01, w23);
        } else {
#pragma unroll
          for (int r = 0; r < 4; ++r){
            const float v = acc[m][n][r];
            const float part = __shfl_xor(v, 1);
            const int nn = nn0 + r;
            const int pidx = (b*N_ + nn)*32 + (d >> 1);
            const float c = cosT[pidx], sn = sinT[pidx];
            const float rot = (d & 1) ? (v*c + part*sn) : (v*c - part*sn);
            const u16 val = f2bf(rot);
            if (s3 == 0) qo[(hb*N_ + nn)*64 + d] = val;
            else         ko[(hb*N_ + nn)*64 + d] = val;
          }
        }
      } else {
#pragma unroll
        for (int r = 0; r < 4; ++r){
          const int grow = m0 + wm*(BM/2) + m*16 + g4*4 + r;
          const int gcol = n0 + wn*64 + n*16 + r16;
          outf[(size_t)grow*Nc + gcol] = acc[m][n][r];
        }
      }
    }
  }
}

// ---------------- fused attention: QBLK=128 (8 waves), paired-tile staging ----------------
// R17 body verbatim, but K/V staged two tiles per barrier pair into separate
// buffer sets: barrier+vmcnt-drain count halves (32 -> 16 on longest block).
// grid 512 = 2 blocks/CU (grid-capped) so the extra LDS (50KB) is free.
#define PST 68   // P LDS row stride: 34 dwords -> uniform bank distribution for b64 ops
__global__ __launch_bounds__(512) void k_attn(
    const u16* __restrict__ qb, const u16* __restrict__ kb, const u16* __restrict__ vt,
    const int* __restrict__ mods, u16* __restrict__ xo)
{
  __shared__ u16 lK[2][64*64];
  __shared__ u16 lV[2][64*64];
  __shared__ u16 lP[8*16*PST];
  const int tid = threadIdx.x, wid = tid >> 6, lane = tid & 63;
  const int id = blockIdx.x;          // 0..511
  const int xcd = id & 7, rank = id >> 3;   // rank 0..63 per XCD
  const int bh = xcd + 8*(rank & 3);
  const int qslot = rank >> 2;        // 0..15
  const int tp = (qslot < 8) ? (15 - qslot) : (qslot - 8);  // complementary pairs
  const int b = bh >> 4, h = bh & 15;
  const int r16 = lane & 15, g4 = lane >> 4;
  const int srow = lane >> 3, sch = lane & 7;
  int moff[4], mend[4];
#pragma unroll
  for (int m = 0; m < 4; ++m){
    moff[m] = mods[(b*4+m)*3+1];
    mend[m] = moff[m] + mods[(b*4+m)*3+2];
  }
  const u16* kbase = kb + (size_t)bh*N_*64;
  const u16* vbase = vt + (size_t)bh*64*N_;
  u16* lPw = &lP[wid*16*PST];

  const int q0 = tp*128 + wid*16;     // this wave's 16 q-rows
  const int i  = q0 + r16;            // this lane's q-row
  const int imax = tp*128 + 127;      // block max q-row (block-uniform skip)
  int jmax = 0, jmax0 = 0;
#pragma unroll
  for (int m = 0; m < 4; ++m){
    if (i  >= moff[m]) jmax  = max(jmax,  mend[m]);
    if (q0 >= moff[m]) jmax0 = max(jmax0, mend[m]);
  }
  const int thrmin = max(q0, jmax0 - 1);   // wave-uniform lower bound of thr
  const int thrg = max(i, jmax - 1);       // per-lane keep threshold (global)
  const u16* qrow = qb + ((size_t)bh*N_ + q0 + r16)*64;
  const bf16x8 aq0 = *(const bf16x8*)&qrow[g4*8];
  const bf16x8 aq1 = *(const bf16x8*)&qrow[32 + g4*8];
  f32x4 o[4] = {};
  f32x4 acc_s = {};                      // row-sum accumulator (ones-MFMA)
  bf16x8 ones;
#pragma unroll
  for (int j = 0; j < 8; ++j) ones[j] = (short)0x3F80;  // bf16 1.0

  // g2(s) = 50*tanh(s*0.125/50)*log2e as odd series in s (w = s^2), 2 terms
  const float D1 = 0.18033688011112043f;
  const float D3 = -3.7570183356483704e-07f;

  auto proc = [&](int kt)->bool{
    if (kt*64 <= imax) return true;
    bool p = false;
#pragma unroll
    for (int m = 0; m < 4; ++m)
      if (imax >= moff[m] && kt*64 < mend[m]) p = true;
    return p;
  };

  auto computeHalf = [&](int kt, const u16* lKc, const u16* lVc){
    // S^T = K @ Q^T : lane holds q = q0+r16, k_local = cb*16 + g4*4 + r
    f32x4 s[4] = {};
    __builtin_amdgcn_s_setprio(1);
#pragma unroll
    for (int cb = 0; cb < 4; ++cb){
#pragma unroll
      for (int t = 0; t < 2; ++t){
        int row = cb*16 + r16;
        int ch = (t*4 + g4) ^ (row & 7);
        bf16x8 bk = *(const bf16x8*)&lKc[row*64 + ch*8];
        s[cb] = __builtin_amdgcn_mfma_f32_16x16x32_bf16(bk, t ? aq1 : aq0, s[cb], 0, 0, 0);
      }
    }
    __builtin_amdgcn_s_setprio(0);
    const int thr = thrg - kt*64;                    // keep <=> k_local <= thr
    const bool nomask = (kt*64 + 63 <= thrmin);      // wave-uniform fully-kept tile
#pragma unroll
    for (int cb = 0; cb < 4; ++cb){
      float p[4];
#pragma unroll
      for (int r = 0; r < 4; ++r){
        const float sv = s[cb][r];
        const float w = sv*sv;
        p[r] = EXP2F(sv * fmaf(w, D3, D1));
      }
      if (!nomask){
#pragma unroll
        for (int r = 0; r < 4; ++r)
          p[r] = (cb*16 + g4*4 + r <= thr) ? p[r] : 0.0f;
      }
      uint32_t w01, w23;
      asm("v_cvt_pk_bf16_f32 %0, %1, %2" : "=v"(w01) : "v"(p[0]), "v"(p[1]));
      asm("v_cvt_pk_bf16_f32 %0, %1, %2" : "=v"(w23) : "v"(p[2]), "v"(p[3]));
      *reinterpret_cast<uint2*>(&lPw[r16*PST + cb*16 + g4*4]) = make_uint2(w01, w23);
    }
    asm volatile("s_waitcnt lgkmcnt(0)" ::: "memory");
    __builtin_amdgcn_sched_barrier(0);
    union { uint2 hh[2]; bf16x8 v; } u0, u1;
    u0.hh[0] = *(const uint2*)&lPw[r16*PST + g4*8];
    u0.hh[1] = *(const uint2*)&lPw[r16*PST + g4*8 + 4];
    u1.hh[0] = *(const uint2*)&lPw[r16*PST + 32 + g4*8];
    u1.hh[1] = *(const uint2*)&lPw[r16*PST + 32 + g4*8 + 4];
    __builtin_amdgcn_s_setprio(1);
    acc_s = __builtin_amdgcn_mfma_f32_16x16x32_bf16(u0.v, ones, acc_s, 0, 0, 0);
    acc_s = __builtin_amdgcn_mfma_f32_16x16x32_bf16(u1.v, ones, acc_s, 0, 0, 0);
#pragma unroll
    for (int cb = 0; cb < 4; ++cb){
#pragma unroll
      for (int t = 0; t < 2; ++t){
        int d = cb*16 + r16;
        int ch = (t*4 + g4) ^ (d & 7);
        bf16x8 bv = *(const bf16x8*)&lVc[d*64 + ch*8];
        o[cb] = __builtin_amdgcn_mfma_f32_16x16x32_bf16(t ? u1.v : u0.v, bv, o[cb], 0, 0, 0);
      }
    }
    __builtin_amdgcn_s_setprio(0);
  };

  for (int pt = 0; pt < 16; ++pt){
    const int ktA = pt*2, ktB = pt*2 + 1;
    const bool pA = proc(ktA);
    const bool pB = proc(ktB);
    if (!(pA || pB)) continue;          // block-uniform skip (whole pair dead)
    __syncthreads();                    // previous-pair readers done
    {
      const int gch = sch ^ srow;
      if (pA){
        GLL16(kbase + (size_t)(ktA*64 + wid*8 + srow)*64 + gch*8, &lK[0][wid*512]);
        GLL16(vbase + (size_t)(wid*8 + srow)*N_ + ktA*64 + gch*8, &lV[0][wid*512]);
      }
      if (pB){
        GLL16(kbase + (size_t)(ktB*64 + wid*8 + srow)*64 + gch*8, &lK[1][wid*512]);
        GLL16(vbase + (size_t)(wid*8 + srow)*N_ + ktB*64 + gch*8, &lV[1][wid*512]);
      }
    }
    __syncthreads();                    // both tiles staged (one vmcnt drain)
    if (pA) computeHalf(ktA, lK[0], lV[0]);
    if (pB) computeHalf(ktB, lK[1], lV[1]);
  }
  // acc_s[r] = full row-sum for q-row g4*4+r (replicated across col lanes)
#pragma unroll
  for (int r = 0; r < 4; ++r){
    const float linv = RCPF(acc_s[r]);
    const int iq = q0 + g4*4 + r;
#pragma unroll
    for (int cb = 0; cb < 4; ++cb)
      xo[(size_t)(b*N_ + iq)*DIM_ + h*64 + cb*16 + r16] = f2bf(o[cb][r]*linv);
  }
}

extern "C" void kernel_launch(void* const* d_in, const int* in_sizes, int n_in,
                              void* d_out, int out_size, void* d_ws, size_t ws_size,
                              hipStream_t stream){
  const float* x     = (const float*)d_in[0];
  const int*   mods  = (const int*)d_in[1];
  const float* gamma = (const float*)d_in[2];
  const float* wqkv  = (const float*)d_in[3];
  const float* wout  = (const float*)d_in[4];
  float* outp = (float*)d_out;

  char* p = (char*)d_ws;
  auto alloc = [&](size_t bytes) -> char* {
    char* r = p; p += (bytes + 255) & ~(size_t)255; return r;
  };
  float* cosT  = (float*)alloc((size_t)B_*N_*32*4);
  float* sinT  = (float*)alloc((size_t)B_*N_*32*4);
  u16* wqkvT   = (u16*)alloc((size_t)NH3*DIM_*2);
  u16* woutT   = (u16*)alloc((size_t)DIM_*DIM_*2);
  u16* xn      = (u16*)alloc((size_t)ROWS*DIM_*2);
  u16* qbb     = (u16*)alloc((size_t)BHN*64*2);
  u16* kbb     = (u16*)alloc((size_t)BHN*64*2);
  u16* vtb     = (u16*)alloc((size_t)BHN*64*2);
  u16* xo      = (u16*)alloc((size_t)ROWS*DIM_*2);

  k_prep<<<8704, 256, 0, stream>>>(x, gamma, wqkv, wout, mods, xn, wqkvT, woutT, cosT, sinT);
  k_gemm<0,128><<<dim3(ROWS/128, NH3/128), 256, 0, stream>>>(xn, wqkvT, DIM_, NH3, nullptr, cosT, sinT, qbb, kbb, vtb);
  k_attn<<<512, 512, 0, stream>>>(qbb, kbb, vtb, mods, xo);
  k_gemm<1,64><<<dim3(ROWS/64, DIM_/128), 256, 0, stream>>>(xo, woutT, DIM_, DIM_, outp, nullptr, nullptr, nullptr, nullptr, nullptr);
}

// Round 22
// 110.669 us; speedup vs baseline: 1.1788x; 1.0217x over previous
//
#include <hip/hip_runtime.h>
#include <hip/hip_bf16.h>
#include <stdint.h>

#define B_ 2
#define N_ 2048
#define H_ 16
#define DIM_ 1024
#define NH3 3072
#define ROWS (B_*N_)   // 4096
#define BHN (B_*H_*N_) // 65536

typedef __attribute__((ext_vector_type(8))) short bf16x8;
typedef __attribute__((ext_vector_type(4))) float f32x4;
typedef unsigned short u16;

__device__ __forceinline__ u16 f2bf(float f){
  union { float f; uint32_t u; } v; v.f = f;
  return (u16)((v.u + 0x7fffu + ((v.u >> 16) & 1u)) >> 16);
}

#if __has_builtin(__builtin_amdgcn_exp2f)
#define EXP2F(x) __builtin_amdgcn_exp2f(x)
#else
#define EXP2F(x) __expf((x) * 0.6931471805599453f)
#endif
#if __has_builtin(__builtin_amdgcn_rcpf)
#define RCPF(x) __builtin_amdgcn_rcpf(x)
#else
#define RCPF(x) (1.0f / (x))
#endif

#define GLL16(g, l) __builtin_amdgcn_global_load_lds( \
    (const __attribute__((address_space(1))) void*)(g), \
    (__attribute__((address_space(3))) void*)(l), 16, 0, 0)

// ---------------- fused prep: rmsnorm (0..4095) | transpose (4096..8191) | rope (8192..8703) ----------------
__global__ __launch_bounds__(256) void k_prep(
    const float* __restrict__ x, const float* __restrict__ gamma,
    const float* __restrict__ wqkv, const float* __restrict__ wout,
    const int* __restrict__ mods,
    u16* __restrict__ xn, u16* __restrict__ wqkvT, u16* __restrict__ woutT,
    float* __restrict__ cosT, float* __restrict__ sinT)
{
  __shared__ float tile[32][33];
  const int bx = blockIdx.x;
  const int tid = threadIdx.x;
  if (bx < 4096){
    const int row = bx;
    const float4 xv = ((const float4*)(x + (size_t)row*DIM_))[tid];
    float ss = xv.x*xv.x + xv.y*xv.y + xv.z*xv.z + xv.w*xv.w;
#pragma unroll
    for (int d = 1; d < 64; d <<= 1) ss += __shfl_xor(ss, d);
    if ((tid & 63) == 0) tile[1][tid >> 6] = ss;
    __syncthreads();
    float tot = tile[1][0] + tile[1][1] + tile[1][2] + tile[1][3];
    float scl = 32.0f / fmaxf(sqrtf(tot), 1e-12f);   // sqrt(1024)=32
    const float4 gv = ((const float4*)gamma)[tid];
    ushort4 o;
    o.x = f2bf(xv.x * scl * (gv.x + 1.0f));
    o.y = f2bf(xv.y * scl * (gv.y + 1.0f));
    o.z = f2bf(xv.z * scl * (gv.z + 1.0f));
    o.w = f2bf(xv.w * scl * (gv.w + 1.0f));
    ((ushort4*)(xn + (size_t)row*DIM_))[tid] = o;
  } else if (bx < 8192){
    const int t = bx - 4096;
    const int bxx = t & 127, by = t >> 7;
    const float* src; u16* dst; int C, bc;
    if (bxx < 96){ src = wqkv; dst = wqkvT; C = NH3;  bc = bxx*32; }
    else         { src = wout; dst = woutT; C = DIM_; bc = (bxx-96)*32; }
    const int R = DIM_;
    const int tx = tid & 31, ty = tid >> 5;
    const int br = by * 32;
#pragma unroll
    for (int i = 0; i < 32; i += 8)
      tile[ty + i][tx] = src[(size_t)(br + ty + i)*C + bc + tx];
    __syncthreads();
#pragma unroll
    for (int i = 0; i < 32; i += 8)
      dst[(size_t)(bc + ty + i)*R + br + tx] = f2bf(tile[tx][ty + i]);
  } else {
    const int t = (bx - 8192)*256 + tid;
    const int f = t & 31, bn = t >> 5;
    const int b = bn >> 11, n = bn & (N_-1);
    int cum = 0;
#pragma unroll
    for (int m = 0; m < 4; ++m){
      const int off = mods[(b*4 + m)*3 + 1];
      const int len = mods[(b*4 + m)*3 + 2];
      cum += min(max(n - off, 0), len - 1);
    }
    const float pos = (float)(n - cum);
    const float inv = powf(10000.0f, -(float)(2*f) / 64.0f);
    float s, c;
    sincosf(pos * inv, &s, &c);
    cosT[t] = c; sinT[t] = s;
  }
}

// ---------------- BMx128 bf16 MFMA GEMM: C = A @ Bt^T ----------------
// PAIR=1: stage two K-steps per barrier pair into separate buffers (halves drains)
template<int MODE, int BM, int PAIR>
__global__ __launch_bounds__(256) void k_gemm(
    const u16* __restrict__ A, const u16* __restrict__ Bt,
    int K, int Nc,
    float* __restrict__ outf,
    const float* __restrict__ cosT, const float* __restrict__ sinT,
    u16* __restrict__ qo, u16* __restrict__ ko, u16* __restrict__ vt)
{
  constexpr int MR = BM/32;
  constexpr int RA = BM/8;
  constexpr int CNT = (RA + 16)/4;
  __shared__ u16 lA[PAIR+1][BM*64];
  __shared__ u16 lB[PAIR+1][128*64];
  const int tid = threadIdx.x;
  const int wid = tid >> 6, lane = tid & 63;
  const int nx = gridDim.x;
  const int orig = blockIdx.y * nx + blockIdx.x;
  const int qq = (nx * gridDim.y) >> 3;
  const int wgid = (orig & 7) * qq + (orig >> 3);
  const int m0 = (wgid % nx) * BM, n0 = (wgid / nx) * 128;
  const int wm = wid >> 1, wn = wid & 1;
  const int srow = lane >> 3, sch = lane & 7;
  const int r16 = lane & 15, g4 = lane >> 4;
  f32x4 acc[MR][4] = {};
  const int ksteps = K >> 6;

  auto stage2 = [&](int kt, int bi){
    const int kb = kt*64;
    const int gch = sch ^ srow;
#pragma unroll
    for (int i = 0; i < CNT; ++i){
      const int reg = wid*CNT + i;
      if (reg < RA){
        const int row = reg*8 + srow;
        GLL16(A + (size_t)(m0 + row)*K + kb + gch*8, &lA[bi][reg*512]);
      } else {
        const int r2 = reg - RA;
        const int row = r2*8 + srow;
        GLL16(Bt + (size_t)(n0 + row)*K + kb + gch*8, &lB[bi][r2*512]);
      }
    }
  };
  auto compute = [&](int bi){
#pragma unroll
    for (int t = 0; t < 2; ++t){
      bf16x8 af[MR], bfr[4];
#pragma unroll
      for (int m = 0; m < MR; ++m){
        int row = wm*(BM/2) + m*16 + r16;
        int ch = (t*4 + g4) ^ (r16 & 7);
        af[m] = *(const bf16x8*)&lA[bi][row*64 + ch*8];
      }
#pragma unroll
      for (int n = 0; n < 4; ++n){
        int row = wn*64 + n*16 + r16;
        int ch = (t*4 + g4) ^ (r16 & 7);
        bfr[n] = *(const bf16x8*)&lB[bi][row*64 + ch*8];
      }
#pragma unroll
      for (int m = 0; m < MR; ++m)
#pragma unroll
        for (int n = 0; n < 4; ++n)
          acc[m][n] = __builtin_amdgcn_mfma_f32_16x16x32_bf16(af[m], bfr[n], acc[m][n], 0, 0, 0);
    }
  };

  if constexpr (PAIR){
    for (int kt = 0; kt < ksteps; kt += 2){
      __syncthreads();                 // previous-pair readers done
      stage2(kt, 0);
      stage2(kt + 1, 1);
      __syncthreads();                 // both staged (one vmcnt drain)
      compute(0);
      compute(1);
    }
  } else {
    for (int kt = 0; kt < ksteps; ++kt){
      __syncthreads();
      stage2(kt, 0);
      __syncthreads();
      compute(0);
    }
  }
#pragma unroll
  for (int m = 0; m < MR; ++m){
#pragma unroll
    for (int n = 0; n < 4; ++n){
      if constexpr (MODE == 0){
        const int gcol = n0 + wn*64 + n*16 + r16;
        const int s3 = gcol >> 10, hh = (gcol >> 6) & 15, d = gcol & 63;
        const int grow0 = m0 + wm*(BM/2) + m*16 + g4*4;
        const int b = grow0 >> 11, nn0 = grow0 & (N_-1);
        const size_t hb = (size_t)(b*H_ + hh);
        if (s3 == 2){
          uint32_t w01, w23;
          asm("v_cvt_pk_bf16_f32 %0, %1, %2" : "=v"(w01) : "v"(acc[m][n][0]), "v"(acc[m][n][1]));
          asm("v_cvt_pk_bf16_f32 %0, %1, %2" : "=v"(w23) : "v"(acc[m][n][2]), "v"(acc[m][n][3]));
          *reinterpret_cast<uint2*>(&vt[(hb*64 + d)*N_ + nn0]) = make_uint2(w01, w23);
        } else {
#pragma unroll
          for (int r = 0; r < 4; ++r){
            const float v = acc[m][n][r];
            const float part = __shfl_xor(v, 1);
            const int nn = nn0 + r;
            const int pidx = (b*N_ + nn)*32 + (d >> 1);
            const float c = cosT[pidx], sn = sinT[pidx];
            const float rot = (d & 1) ? (v*c + part*sn) : (v*c - part*sn);
            const u16 val = f2bf(rot);
            if (s3 == 0) qo[(hb*N_ + nn)*64 + d] = val;
            else         ko[(hb*N_ + nn)*64 + d] = val;
          }
        }
      } else {
#pragma unroll
        for (int r = 0; r < 4; ++r){
          const int grow = m0 + wm*(BM/2) + m*16 + g4*4 + r;
          const int gcol = n0 + wn*64 + n*16 + r16;
          outf[(size_t)grow*Nc + gcol] = acc[m][n][r];
        }
      }
    }
  }
}

// ---------------- fused attention: QBLK=128 (8 waves), triple-tile staging ----------------
// R20 mechanism extended: stage up to THREE tiles per barrier pair into
// separate buffer sets (LDS 65.4KB, still 2 blocks/CU since grid-capped).
#define PST 68   // P LDS row stride: 34 dwords -> uniform bank distribution for b64 ops
__global__ __launch_bounds__(512) void k_attn(
    const u16* __restrict__ qb, const u16* __restrict__ kb, const u16* __restrict__ vt,
    const int* __restrict__ mods, u16* __restrict__ xo)
{
  __shared__ u16 lK[3][64*64];
  __shared__ u16 lV[3][64*64];
  __shared__ u16 lP[8*16*PST];
  const int tid = threadIdx.x, wid = tid >> 6, lane = tid & 63;
  const int id = blockIdx.x;          // 0..511
  const int xcd = id & 7, rank = id >> 3;   // rank 0..63 per XCD
  const int bh = xcd + 8*(rank & 3);
  const int qslot = rank >> 2;        // 0..15
  const int tp = (qslot < 8) ? (15 - qslot) : (qslot - 8);  // complementary pairs
  const int b = bh >> 4, h = bh & 15;
  const int r16 = lane & 15, g4 = lane >> 4;
  const int srow = lane >> 3, sch = lane & 7;
  int moff[4], mend[4];
#pragma unroll
  for (int m = 0; m < 4; ++m){
    moff[m] = mods[(b*4+m)*3+1];
    mend[m] = moff[m] + mods[(b*4+m)*3+2];
  }
  const u16* kbase = kb + (size_t)bh*N_*64;
  const u16* vbase = vt + (size_t)bh*64*N_;
  u16* lPw = &lP[wid*16*PST];

  const int q0 = tp*128 + wid*16;     // this wave's 16 q-rows
  const int i  = q0 + r16;            // this lane's q-row
  const int imax = tp*128 + 127;      // block max q-row (block-uniform skip)
  int jmax = 0, jmax0 = 0;
#pragma unroll
  for (int m = 0; m < 4; ++m){
    if (i  >= moff[m]) jmax  = max(jmax,  mend[m]);
    if (q0 >= moff[m]) jmax0 = max(jmax0, mend[m]);
  }
  const int thrmin = max(q0, jmax0 - 1);   // wave-uniform lower bound of thr
  const int thrg = max(i, jmax - 1);       // per-lane keep threshold (global)
  const u16* qrow = qb + ((size_t)bh*N_ + q0 + r16)*64;
  const bf16x8 aq0 = *(const bf16x8*)&qrow[g4*8];
  const bf16x8 aq1 = *(const bf16x8*)&qrow[32 + g4*8];
  f32x4 o[4] = {};
  f32x4 acc_s = {};                      // row-sum accumulator (ones-MFMA)
  bf16x8 ones;
#pragma unroll
  for (int j = 0; j < 8; ++j) ones[j] = (short)0x3F80;  // bf16 1.0

  // g2(s) = 50*tanh(s*0.125/50)*log2e as odd series in s (w = s^2), 2 terms
  const float D1 = 0.18033688011112043f;
  const float D3 = -3.7570183356483704e-07f;

  auto proc = [&](int kt)->bool{
    if (kt >= 32) return false;
    if (kt*64 <= imax) return true;
    bool p = false;
#pragma unroll
    for (int m = 0; m < 4; ++m)
      if (imax >= moff[m] && kt*64 < mend[m]) p = true;
    return p;
  };

  auto computeHalf = [&](int kt, const u16* lKc, const u16* lVc){
    // S^T = K @ Q^T : lane holds q = q0+r16, k_local = cb*16 + g4*4 + r
    f32x4 s[4] = {};
    __builtin_amdgcn_s_setprio(1);
#pragma unroll
    for (int cb = 0; cb < 4; ++cb){
#pragma unroll
      for (int t = 0; t < 2; ++t){
        int row = cb*16 + r16;
        int ch = (t*4 + g4) ^ (row & 7);
        bf16x8 bk = *(const bf16x8*)&lKc[row*64 + ch*8];
        s[cb] = __builtin_amdgcn_mfma_f32_16x16x32_bf16(bk, t ? aq1 : aq0, s[cb], 0, 0, 0);
      }
    }
    __builtin_amdgcn_s_setprio(0);
    const int thr = thrg - kt*64;                    // keep <=> k_local <= thr
    const bool nomask = (kt*64 + 63 <= thrmin);      // wave-uniform fully-kept tile
#pragma unroll
    for (int cb = 0; cb < 4; ++cb){
      float p[4];
#pragma unroll
      for (int r = 0; r < 4; ++r){
        const float sv = s[cb][r];
        const float w = sv*sv;
        p[r] = EXP2F(sv * fmaf(w, D3, D1));
      }
      if (!nomask){
#pragma unroll
        for (int r = 0; r < 4; ++r)
          p[r] = (cb*16 + g4*4 + r <= thr) ? p[r] : 0.0f;
      }
      uint32_t w01, w23;
      asm("v_cvt_pk_bf16_f32 %0, %1, %2" : "=v"(w01) : "v"(p[0]), "v"(p[1]));
      asm("v_cvt_pk_bf16_f32 %0, %1, %2" : "=v"(w23) : "v"(p[2]), "v"(p[3]));
      *reinterpret_cast<uint2*>(&lPw[r16*PST + cb*16 + g4*4]) = make_uint2(w01, w23);
    }
    asm volatile("s_waitcnt lgkmcnt(0)" ::: "memory");
    __builtin_amdgcn_sched_barrier(0);
    union { uint2 hh[2]; bf16x8 v; } u0, u1;
    u0.hh[0] = *(const uint2*)&lPw[r16*PST + g4*8];
    u0.hh[1] = *(const uint2*)&lPw[r16*PST + g4*8 + 4];
    u1.hh[0] = *(const uint2*)&lPw[r16*PST + 32 + g4*8];
    u1.hh[1] = *(const uint2*)&lPw[r16*PST + 32 + g4*8 + 4];
    __builtin_amdgcn_s_setprio(1);
    acc_s = __builtin_amdgcn_mfma_f32_16x16x32_bf16(u0.v, ones, acc_s, 0, 0, 0);
    acc_s = __builtin_amdgcn_mfma_f32_16x16x32_bf16(u1.v, ones, acc_s, 0, 0, 0);
#pragma unroll
    for (int cb = 0; cb < 4; ++cb){
#pragma unroll
      for (int t = 0; t < 2; ++t){
        int d = cb*16 + r16;
        int ch = (t*4 + g4) ^ (d & 7);
        bf16x8 bv = *(const bf16x8*)&lVc[d*64 + ch*8];
        o[cb] = __builtin_amdgcn_mfma_f32_16x16x32_bf16(t ? u1.v : u0.v, bv, o[cb], 0, 0, 0);
      }
    }
    __builtin_amdgcn_s_setprio(0);
  };

  auto stage = [&](int kt, int bi){
    const int gch = sch ^ srow;
    GLL16(kbase + (size_t)(kt*64 + wid*8 + srow)*64 + gch*8, &lK[bi][wid*512]);
    GLL16(vbase + (size_t)(wid*8 + srow)*N_ + kt*64 + gch*8, &lV[bi][wid*512]);
  };

  for (int base = 0; base < 32; base += 3){
    const bool pA = proc(base);
    const bool pB = proc(base + 1);
    const bool pC = proc(base + 2);
    if (!(pA || pB || pC)) continue;    // block-uniform skip (whole group dead)
    __syncthreads();                    // previous-group readers done
    if (pA) stage(base,     0);
    if (pB) stage(base + 1, 1);
    if (pC) stage(base + 2, 2);
    __syncthreads();                    // all staged (one vmcnt drain)
    if (pA) computeHalf(base,     lK[0], lV[0]);
    if (pB) computeHalf(base + 1, lK[1], lV[1]);
    if (pC) computeHalf(base + 2, lK[2], lV[2]);
  }
  // acc_s[r] = full row-sum for q-row g4*4+r (replicated across col lanes)
#pragma unroll
  for (int r = 0; r < 4; ++r){
    const float linv = RCPF(acc_s[r]);
    const int iq = q0 + g4*4 + r;
#pragma unroll
    for (int cb = 0; cb < 4; ++cb)
      xo[(size_t)(b*N_ + iq)*DIM_ + h*64 + cb*16 + r16] = f2bf(o[cb][r]*linv);
  }
}

extern "C" void kernel_launch(void* const* d_in, const int* in_sizes, int n_in,
                              void* d_out, int out_size, void* d_ws, size_t ws_size,
                              hipStream_t stream){
  const float* x     = (const float*)d_in[0];
  const int*   mods  = (const int*)d_in[1];
  const float* gamma = (const float*)d_in[2];
  const float* wqkv  = (const float*)d_in[3];
  const float* wout  = (const float*)d_in[4];
  float* outp = (float*)d_out;

  char* p = (char*)d_ws;
  auto alloc = [&](size_t bytes) -> char* {
    char* r = p; p += (bytes + 255) & ~(size_t)255; return r;
  };
  float* cosT  = (float*)alloc((size_t)B_*N_*32*4);
  float* sinT  = (float*)alloc((size_t)B_*N_*32*4);
  u16* wqkvT   = (u16*)alloc((size_t)NH3*DIM_*2);
  u16* woutT   = (u16*)alloc((size_t)DIM_*DIM_*2);
  u16* xn      = (u16*)alloc((size_t)ROWS*DIM_*2);
  u16* qbb     = (u16*)alloc((size_t)BHN*64*2);
  u16* kbb     = (u16*)alloc((size_t)BHN*64*2);
  u16* vtb     = (u16*)alloc((size_t)BHN*64*2);
  u16* xo      = (u16*)alloc((size_t)ROWS*DIM_*2);

  k_prep<<<8704, 256, 0, stream>>>(x, gamma, wqkv, wout, mods, xn, wqkvT, woutT, cosT, sinT);
  k_gemm<0,128,0><<<dim3(ROWS/128, NH3/128), 256, 0, stream>>>(xn, wqkvT, DIM_, NH3, nullptr, cosT, sinT, qbb, kbb, vtb);
  k_attn<<<512, 512, 0, stream>>>(qbb, kbb, vtb, mods, xo);
  k_gemm<1,64,1><<<dim3(ROWS/64, DIM_/128), 256, 0, stream>>>(xo, woutT, DIM_, DIM_, outp, nullptr, nullptr, nullptr, nullptr, nullptr);
}